// Round 15
// baseline (1143.638 us; speedup 1.0000x reference)
//
#include <hip/hip_runtime.h>

// Persistent LSTM decoder, FUSED gate+logit WGs, fp16 datapath, 4 batch-groups,
// XCD-swizzled (group on 2 XCDs). 256 WGs x 256 thr (4 waves = k-quarters).
// r15: per-wave producer-subset spin (16 flags = 1 line each) with h-load+MFMA
// BEFORE the first barrier (jitter absorbed once at B1); pointwise concentrated
// in wave 0 (4 cells/lane) publishing h DIRECTLY from registers (8B/lane sc1,
// coalesced 512B) -> drain -> flag; waves 1-3 enter logit MFMAs at B2 (separate
// glo buffer). 3 barriers/step. Acquire fence every FCAD steps (per wave).
// Packed 4B flags, no RMW anywhere. Protocol staleness bound as r12-r14.

#define TT 256
#define NH 1024
#define NV 1000
#define WROW 2024   // V + H
#define NGRP 4
#define GPW 64      // WGs per group
#define GB 16       // batches per group

typedef __attribute__((ext_vector_type(8))) short short8;
typedef __attribute__((ext_vector_type(8))) _Float16 half8;
typedef __attribute__((ext_vector_type(4))) float f32x4;

#define AGT __HIP_MEMORY_SCOPE_AGENT

__device__ __forceinline__ unsigned short f2bf(float f) {
    unsigned int u = __float_as_uint(f);
    u += 0x7fffu + ((u >> 16) & 1u);
    return (unsigned short)(u >> 16);
}
__device__ __forceinline__ float bf2f(unsigned short s) {
    return __uint_as_float(((unsigned int)s) << 16);
}
__device__ __forceinline__ unsigned short f2h(float f) {
    return __builtin_bit_cast(unsigned short, (_Float16)f);
}
__device__ __forceinline__ half8 as_h8(short8 s) {
    return __builtin_bit_cast(half8, s);
}
__device__ __forceinline__ float sigm(float x) {
    return __builtin_amdgcn_rcpf(1.0f + __expf(-x));
}
__device__ __forceinline__ float tanh_f(float x) {
    return 2.0f * __builtin_amdgcn_rcpf(1.0f + __expf(-2.0f * x)) - 1.0f;
}

// ---- one-time: transpose-cast embedding block Ww[:, :V] -> embT[V][4096] bf16
__global__ void embT_kernel(const float* __restrict__ Ww, unsigned short* __restrict__ embT) {
    __shared__ unsigned short tile[64][80];
    const int rt = blockIdx.x & 63, vt = blockIdx.x >> 6;
    const int r0 = rt * 64, v0 = vt * 64;
    const int t = threadIdx.x;
    {
        int rr = t >> 2, c0 = (t & 3) * 16;
        for (int j = 0; j < 16; ++j) {
            int v = v0 + c0 + j;
            float x = (v < NV) ? Ww[(size_t)(r0 + rr) * WROW + v] : 0.f;
            tile[c0 + j][rr] = f2bf(x);
        }
    }
    __syncthreads();
    {
        int vv = t >> 2, k0 = (t & 3) * 16;
        int v = v0 + vv;
        if (v < NV)
            for (int j = 0; j < 16; ++j)
                embT[(size_t)v * 4096 + r0 + k0 + j] = tile[vv][k0 + j];
    }
}

// ---- one-time: enc_h -> blocked fp16 slot 0 of each group's ring
__global__ void h0_kernel(const float* __restrict__ enc_h, unsigned short* __restrict__ hring,
                          int ring) {
    int i = blockIdx.x * 256 + threadIdx.x;  // 0..65535 over [64 b][1024 u]
    int b = i >> 10, u = i & 1023;
    int g = b >> 4, bl = b & 15;
    hring[(size_t)g * ring * 16384 + ((u >> 4) << 8) + (bl << 4) + (u & 15)] = f2h(enc_h[i]);
}

template <int RING, int FCAD>
__global__ void __launch_bounds__(256, 1)
lstm_kernel(const float* __restrict__ enc_c,
            const int* __restrict__ trg,
            const float* __restrict__ Ww,
            const float* __restrict__ Wb,
            const float* __restrict__ fcw,
            const float* __restrict__ fcb,
            const unsigned short* __restrict__ embT,
            unsigned short* __restrict__ hring,
            int* __restrict__ syn,
            float* __restrict__ out) {
    __shared__ unsigned short smw[65536];   // 128 KB: fp16 gate weights, XOR-swizzled
    __shared__ float gl[4][4][16][18];      // gate partial planes [kq4][gate][row][col+pad]
    __shared__ float glo[4][16][18];        // logit partial planes [kq4][row][col+pad]

    // XCD swizzle: group g occupies XCDs {2g, 2g+1} (dispatch: xcd = blockIdx % 8)
    const int pb = blockIdx.x;
    const int xcd = pb & 7;
    const int g = xcd >> 1;
    const int iw = ((xcd & 1) << 5) + (pb >> 3);  // WG within group, 0..63
    const int tid = threadIdx.x;
    const int wv = tid >> 6;      // 0..3 = k-quarter
    const int lane = tid & 63;
    const int ml = lane & 15;
    const int kq = lane >> 4;
    const int kl8 = kq * 8;
    const int rq = kq * 4;
    const int gB = g * GB;
    int* gfl4 = syn + g * 64;     // this group's 64 epoch flags, packed 4B
    unsigned short* hbase = hring + (size_t)g * RING * 16384;

    // ============ init: gate weights -> LDS ============
    const int u0 = iw * 16;
    for (int c = tid; c < 8192; c += 256) {
        int row = c >> 7;
        int col8 = (c & 127) << 3;
        int grow = ((row >> 4) << 10) + u0 + (row & 15);
        const float* src = Ww + (size_t)grow * WROW + 1000 + col8;
        float4 a = *(const float4*)src;
        float4 b2 = *(const float4*)(src + 4);
        union { unsigned short us[8]; short8 s; } w;
        w.us[0] = f2h(a.x); w.us[1] = f2h(a.y); w.us[2] = f2h(a.z); w.us[3] = f2h(a.w);
        w.us[4] = f2h(b2.x); w.us[5] = f2h(b2.y); w.us[6] = f2h(b2.z); w.us[7] = f2h(b2.w);
        int byt = ((c & 127) << 4) ^ ((row & 7) << 4);
        *(short8*)(smw + (row << 10) + (byt >> 1)) = w.s;
    }
    // ============ init: logit fc rows [v0, v0+16) -> registers ============
    const int v0 = iw * 16;
    const int vrowc = (v0 + ml < NV) ? v0 + ml : NV - 1;
    half8 la[8];
    #pragma unroll
    for (int j = 0; j < 8; ++j) {
        const float* src = fcw + (size_t)vrowc * NH + (((wv << 3) + j) << 5) + kl8;
        union { unsigned short us[8]; short8 s; } w;
        #pragma unroll
        for (int e = 0; e < 8; ++e) w.us[e] = f2h(src[e]);
        la[j] = as_h8(w.s);
    }
    // wave-0 pointwise roles: lane -> (batch pb_, units pu..pu+3)
    const int pb_ = lane >> 2;
    const int pu = (lane & 3) << 2;
    float bs4[4][4];
    #pragma unroll
    for (int q = 0; q < 4; ++q)
        #pragma unroll
        for (int j = 0; j < 4; ++j)
            bs4[q][j] = Wb[(q << 10) + u0 + pu + j];
    float creg4[4];
    #pragma unroll
    for (int j = 0; j < 4; ++j)
        creg4[j] = enc_c[(size_t)(gB + pb_) * NH + u0 + pu + j];
    // wave-1 store roles
    const int srow = lane >> 2, sseg = lane & 3;
    float fbs[4];
    #pragma unroll
    for (int r = 0; r < 4; ++r) {
        int v = v0 + (sseg << 2) + r;
        fbs[r] = fcb[v < NV ? v : NV - 1];
    }
    __syncthreads();

    for (int p = 1; p <= TT + 1; ++p) {
        // wave-0 embedding prefetch (16 values/lane; latency hides under spin)
        unsigned short emb4[4][4];
        if (wv == 0 && p <= TT) {
            int idx = trg[(gB + pb_) * TT + p - 1];
            #pragma unroll
            for (int q = 0; q < 4; ++q)
                #pragma unroll
                for (int j = 0; j < 4; ++j)
                    emb4[q][j] = embT[(size_t)idx * 4096 + (q << 10) + u0 + pu + j];
        }
        // staleness-bounding acquire (per wave, every FCAD steps), BEFORE the spin
        if (FCAD == 1 || (p & (FCAD - 1)) == 1)
            __builtin_amdgcn_fence(__ATOMIC_ACQUIRE, "agent");
        // per-wave producer-subset spin: this wave reads h blocks [16wv,16wv+16)
        if (p > 1) {
            const int* f = gfl4 + (wv << 4) + (lane & 15);
            while (__hip_atomic_load(f, __ATOMIC_RELAXED, AGT) < p - 1) { }
        }
        asm volatile("" ::: "memory");   // forbid hoisting h loads above the spin

        const unsigned short* hh = hbase + (size_t)((p - 1) & (RING - 1)) * 16384;
        half8 hb[8];
        #pragma unroll
        for (int j = 0; j < 8; ++j) {
            int wgp = (wv << 4) + (j << 1) + (kq >> 1);
            hb[j] = as_h8(*(const short8*)(hh + (wgp << 8) + (ml << 4) + ((kq & 1) << 3)));
        }
        // gate MFMAs into registers (no LDS writes yet -> before any barrier)
        f32x4 acc[4] = {};
        if (p <= TT) {
            #pragma unroll
            for (int j = 0; j < 8; ++j) {
                int kb = (((wv << 3) + j) << 5) + kl8;
                #pragma unroll
                for (int rt = 0; rt < 4; ++rt) {
                    int row = (rt << 4) + ml;
                    int byt = (kb << 1) ^ ((row & 7) << 4);
                    half8 a = as_h8(*(const short8*)(smw + (row << 10) + (byt >> 1)));
                    acc[rt] = __builtin_amdgcn_mfma_f32_16x16x32_f16(a, hb[j], acc[rt], 0, 0, 0);
                }
            }
        }
        __syncthreads();   // B1: prev wave0 gl reads + prev wave1 glo reads complete
        if (p <= TT) {
            #pragma unroll
            for (int rt = 0; rt < 4; ++rt)
                #pragma unroll
                for (int r = 0; r < 4; ++r)
                    gl[wv][rt][rq + r][ml] = acc[rt][r];
        }
        __syncthreads();   // B2: gl ready

        // ---- wave 0: pointwise x4 cells -> direct register publish -> flag ----
        if (p <= TT && wv == 0) {
            unsigned long long hw = 0;
            #pragma unroll
            for (int j = 0; j < 4; ++j) {
                int u = pu + j;
                float pre[4];
                #pragma unroll
                for (int q = 0; q < 4; ++q)
                    pre[q] = gl[0][q][u][pb_] + gl[1][q][u][pb_] + gl[2][q][u][pb_]
                           + gl[3][q][u][pb_] + bs4[q][j] + bf2f(emb4[q][j]);
                float ii = sigm(pre[0]), ff = sigm(pre[1]);
                float gg = tanh_f(pre[2]), oo = sigm(pre[3]);
                float cc = ff * creg4[j] + ii * gg;
                creg4[j] = cc;
                hw |= (unsigned long long)f2h(oo * tanh_f(cc)) << (j * 16);
            }
            unsigned short* dst = hbase + (size_t)(p & (RING - 1)) * 16384
                                  + (iw << 8) + (lane << 2);
            __hip_atomic_store((unsigned long long*)dst, hw, __ATOMIC_RELAXED, AGT);
            asm volatile("s_waitcnt vmcnt(0)" ::: "memory");  // wave-0 stores acked
            if (lane == 0)
                __hip_atomic_store(gfl4 + iw, p, __ATOMIC_RELAXED, AGT);  // RELEASE
        }

        // ---- logit phase for t = p-2 (all waves; separate glo buffer) ----
        if (p >= 2) {
            f32x4 accl = {};
            #pragma unroll
            for (int j = 0; j < 8; ++j)
                accl = __builtin_amdgcn_mfma_f32_16x16x32_f16(la[j], hb[j], accl, 0, 0, 0);
            #pragma unroll
            for (int r = 0; r < 4; ++r)
                glo[wv][rq + r][ml] = accl[r];
            __syncthreads();   // B5: glo ready
            // wave 1: fused finalize + full-line nontemporal stores (drain deferred)
            if (wv == 1) {
                int vq = v0 + (sseg << 2);
                f32x4 val;
                #pragma unroll
                for (int r = 0; r < 4; ++r) {
                    int rowi = (sseg << 2) + r;
                    val[r] = glo[0][rowi][srow] + glo[1][rowi][srow]
                           + glo[2][rowi][srow] + glo[3][rowi][srow] + fbs[r];
                }
                float* po = out + ((size_t)(gB + srow) * TT + (p - 2)) * NV + vq;
                if (vq + 3 < NV) {
                    __builtin_nontemporal_store(val, (f32x4*)po);
                } else {
                    #pragma unroll
                    for (int r = 0; r < 4; ++r)
                        if (vq + r < NV) __builtin_nontemporal_store(val[r], po + r);
                }
            }
        }
        // no trailing barrier: next iteration's B1 guards gl/glo reuse
    }
}

extern "C" void kernel_launch(void* const* d_in, const int* in_sizes, int n_in,
                              void* d_out, int out_size, void* d_ws, size_t ws_size,
                              hipStream_t stream) {
    const float* enc_h = (const float*)d_in[0];
    const float* enc_c = (const float*)d_in[1];
    const int* trg = (const int*)d_in[2];
    const float* Ww = (const float*)d_in[3];
    const float* Wb = (const float*)d_in[4];
    const float* fcw = (const float*)d_in[5];
    const float* fcb = (const float*)d_in[6];
    float* out = (float*)d_out;

    unsigned short* embT = (unsigned short*)d_ws;        // 1000 x 4096 bf16 (8 MB)
    unsigned short* hring = embT + (size_t)1000 * 4096;  // [4 grp][RING][16384] fp16

    const size_t embBytes = (size_t)1000 * 4096 * 2;
    const size_t slotBytes = (size_t)16384 * 2;
    const size_t need16 = embBytes + (size_t)NGRP * 16 * slotBytes + 8192;  // ~10.5 MB

    hipLaunchKernelGGL(embT_kernel, dim3(1024), dim3(256), 0, stream, Ww, embT);

    if (ws_size >= need16) {
        int* syn = (int*)(hring + (size_t)NGRP * 16 * 16384);
        hipMemsetAsync(syn, 0, 4096, stream);
        hipLaunchKernelGGL(h0_kernel, dim3(256), dim3(256), 0, stream, enc_h, hring, 16);
        lstm_kernel<16, 8><<<dim3(NGRP * GPW), dim3(256), 0, stream>>>(
            enc_c, trg, Ww, Wb, fcw, fcb, embT, hring, syn, out);
    } else {
        int* syn = (int*)(hring + (size_t)NGRP * 4 * 16384);
        hipMemsetAsync(syn, 0, 4096, stream);
        hipLaunchKernelGGL(h0_kernel, dim3(256), dim3(256), 0, stream, enc_h, hring, 4);
        lstm_kernel<4, 1><<<dim3(NGRP * GPW), dim3(256), 0, stream>>>(
            enc_c, trg, Ww, Wb, fcw, fcb, embT, hring, syn, out);
    }
}

// Round 16
// 822.065 us; speedup vs baseline: 1.3912x; 1.3912x over previous
//
#include <hip/hip_runtime.h>

// Persistent LSTM decoder, FUSED gate+logit WGs, fp16 datapath, coalesced stores,
// FOUR independent batch-groups (16 batches each, own ring+flags).
// 256 WGs x 256 thr (4 waves = k-quarters). XCD-swizzled: each group's 64 WGs
// sit on exactly 2 XCDs (h broadcast L2-local; FETCH 262->96 MB proven r14).
// Each WG owns 16 hidden units (gate weights LDS, XOR-swizzled) and 16 vocab
// rows (fc weights in registers). Partial K-sums via 4 gl planes.
// Critical path: h publish + per-wave vmcnt drain + flag release all in wave 0
// (no barrier before release); waves 1-3 run logit MFMAs during the drain;
// logit finalize/stores on wave 1. Acquire fence BEFORE the spin, every
// FCAD=16 steps (proof: one inv per 16-step window covers slot reuse at
// RING=16, skew<=1; L1 per-CU so wave0's inv covers all waves; B1 orders).
// Packed 4B flags, no RMW anywhere. == r14 (840us proven) + FCAD 8->16.

#define TT 256
#define NH 1024
#define NV 1000
#define WROW 2024   // V + H
#define NGRP 4
#define GPW 64      // WGs per group
#define GB 16       // batches per group

typedef __attribute__((ext_vector_type(8))) short short8;
typedef __attribute__((ext_vector_type(8))) _Float16 half8;
typedef __attribute__((ext_vector_type(4))) float f32x4;

#define AGT __HIP_MEMORY_SCOPE_AGENT

__device__ __forceinline__ unsigned short f2bf(float f) {
    unsigned int u = __float_as_uint(f);
    u += 0x7fffu + ((u >> 16) & 1u);
    return (unsigned short)(u >> 16);
}
__device__ __forceinline__ float bf2f(unsigned short s) {
    return __uint_as_float(((unsigned int)s) << 16);
}
__device__ __forceinline__ unsigned short f2h(float f) {
    return __builtin_bit_cast(unsigned short, (_Float16)f);
}
__device__ __forceinline__ half8 as_h8(short8 s) {
    return __builtin_bit_cast(half8, s);
}
__device__ __forceinline__ float sigm(float x) {
    return __builtin_amdgcn_rcpf(1.0f + __expf(-x));
}
__device__ __forceinline__ float tanh_f(float x) {
    return 2.0f * __builtin_amdgcn_rcpf(1.0f + __expf(-2.0f * x)) - 1.0f;
}

// ---- one-time: transpose-cast embedding block Ww[:, :V] -> embT[V][4096] bf16
__global__ void embT_kernel(const float* __restrict__ Ww, unsigned short* __restrict__ embT) {
    __shared__ unsigned short tile[64][80];
    const int rt = blockIdx.x & 63, vt = blockIdx.x >> 6;
    const int r0 = rt * 64, v0 = vt * 64;
    const int t = threadIdx.x;
    {
        int rr = t >> 2, c0 = (t & 3) * 16;
        for (int j = 0; j < 16; ++j) {
            int v = v0 + c0 + j;
            float x = (v < NV) ? Ww[(size_t)(r0 + rr) * WROW + v] : 0.f;
            tile[c0 + j][rr] = f2bf(x);
        }
    }
    __syncthreads();
    {
        int vv = t >> 2, k0 = (t & 3) * 16;
        int v = v0 + vv;
        if (v < NV)
            for (int j = 0; j < 16; ++j)
                embT[(size_t)v * 4096 + r0 + k0 + j] = tile[vv][k0 + j];
    }
}

// ---- one-time: enc_h -> blocked fp16 slot 0 of each group's ring
__global__ void h0_kernel(const float* __restrict__ enc_h, unsigned short* __restrict__ hring,
                          int ring) {
    int i = blockIdx.x * 256 + threadIdx.x;  // 0..65535 over [64 b][1024 u]
    int b = i >> 10, u = i & 1023;
    int g = b >> 4, bl = b & 15;
    hring[(size_t)g * ring * 16384 + ((u >> 4) << 8) + (bl << 4) + (u & 15)] = f2h(enc_h[i]);
}

template <int RING, int FCAD>
__global__ void __launch_bounds__(256, 1)
lstm_kernel(const float* __restrict__ enc_c,
            const int* __restrict__ trg,
            const float* __restrict__ Ww,
            const float* __restrict__ Wb,
            const float* __restrict__ fcw,
            const float* __restrict__ fcb,
            const unsigned short* __restrict__ embT,
            unsigned short* __restrict__ hring,
            int* __restrict__ syn,
            float* __restrict__ out) {
    __shared__ unsigned short smw[65536];   // 128 KB: fp16 gate weights, XOR-swizzled
    __shared__ float gl[4][4][16][18];      // partial planes [kq4][rt][row][col(+pad)]
    __shared__ unsigned short ht[16][20];   // h staging tile [b][u] (+pad)

    // XCD swizzle: physical block -> (group, iw) s.t. group g occupies XCDs {2g,2g+1}
    const int pb = blockIdx.x;
    const int xcd = pb & 7;
    const int g = xcd >> 1;                 // batch-group
    const int iw = ((xcd & 1) << 5) + (pb >> 3);  // WG within group, 0..63
    const int tid = threadIdx.x;
    const int wv = tid >> 6;      // 0..3 = k-quarter (K range wv*256..+255)
    const int lane = tid & 63;
    const int ml = lane & 15;
    const int kq = lane >> 4;
    const int kl8 = kq * 8;
    const int rq = kq * 4;
    const int gB = g * GB;
    int* gfl4 = syn + g * 64;     // this group's 64 epoch flags, packed 4B
    unsigned short* hbase = hring + (size_t)g * RING * 16384;

    // ============ init: gate weights -> LDS ============
    const int u0 = iw * 16;       // hidden units [u0, u0+16)
    for (int c = tid; c < 8192; c += 256) {   // 64 rows x 1024 fp16 -> LDS
        int row = c >> 7;
        int col8 = (c & 127) << 3;
        int grow = ((row >> 4) << 10) + u0 + (row & 15);   // q*1024 + u0 + uu
        const float* src = Ww + (size_t)grow * WROW + 1000 + col8;
        float4 a = *(const float4*)src;
        float4 b2 = *(const float4*)(src + 4);
        union { unsigned short us[8]; short8 s; } w;
        w.us[0] = f2h(a.x); w.us[1] = f2h(a.y); w.us[2] = f2h(a.z); w.us[3] = f2h(a.w);
        w.us[4] = f2h(b2.x); w.us[5] = f2h(b2.y); w.us[6] = f2h(b2.z); w.us[7] = f2h(b2.w);
        int byt = ((c & 127) << 4) ^ ((row & 7) << 4);
        *(short8*)(smw + (row << 10) + (byt >> 1)) = w.s;
    }
    // ============ init: logit fc rows [v0, v0+16) -> registers (A-fragments) ============
    const int v0 = iw * 16;
    const int vrowc = (v0 + ml < NV) ? v0 + ml : NV - 1;
    half8 la[8];
    #pragma unroll
    for (int j = 0; j < 8; ++j) {
        const float* src = fcw + (size_t)vrowc * NH + (((wv << 3) + j) << 5) + kl8;
        union { unsigned short us[8]; short8 s; } w;
        #pragma unroll
        for (int e = 0; e < 8; ++e) w.us[e] = f2h(src[e]);
        la[j] = as_h8(w.s);
    }
    // pointwise roles: thread -> (group-local batch b, unit u)
    const int b = tid & 15;
    const int u = tid >> 4;       // 0..15
    float bs[4];
    #pragma unroll
    for (int q = 0; q < 4; ++q)
        bs[q] = Wb[(q << 10) + u0 + u];
    float creg = enc_c[(size_t)(gB + b) * NH + u0 + u];
    // store roles (WAVE 1, tid 64..127): srow = batch, sseg = 4-float segment
    const int srow = (tid & 63) >> 2, sseg = tid & 3;
    float fbs[4];
    #pragma unroll
    for (int r = 0; r < 4; ++r) {
        int v = v0 + (sseg << 2) + r;
        fbs[r] = fcb[v < NV ? v : NV - 1];
    }
    __syncthreads();

    for (int p = 1; p <= TT + 1; ++p) {
        // embedding prefetch (plain cached loads; overlap the spin)
        unsigned short emb[4];
        if (p <= TT) {
            int idx = trg[(gB + b) * TT + p - 1];
            #pragma unroll
            for (int q = 0; q < 4; ++q)
                emb[q] = embT[(size_t)idx * 4096 + (q << 10) + u0 + u];
        }
        // wave 0: fence FIRST (inv hides under the spin), then packed-flag polls
        if (tid < 64) {
            if (FCAD == 1 || (p & (FCAD - 1)) == 1)
                __builtin_amdgcn_fence(__ATOMIC_ACQUIRE, "agent");
            if (p > 1)
                while (__hip_atomic_load(gfl4 + tid, __ATOMIC_RELAXED, AGT) < p - 1) { }
        }
        __syncthreads();   // B1: also drains deferred out stores (wave 1)

        const unsigned short* hh = hbase + (size_t)((p - 1) & (RING - 1)) * 16384;
        // this wave's 8 h fragments (K range wv*256..+255), contiguous blocked reads
        half8 hb[8];
        #pragma unroll
        for (int j = 0; j < 8; ++j) {
            int wgp = (wv << 4) + (j << 1) + (kq >> 1);
            hb[j] = as_h8(*(const short8*)(hh + (wgp << 8) + (ml << 4) + ((kq & 1) << 3)));
        }

        // ---------------- gate phase (critical path) ----------------
        if (p <= TT) {
            f32x4 acc[4] = {};
            #pragma unroll
            for (int j = 0; j < 8; ++j) {
                int kb = (((wv << 3) + j) << 5) + kl8;
                #pragma unroll
                for (int rt = 0; rt < 4; ++rt) {
                    int row = (rt << 4) + ml;
                    int byt = (kb << 1) ^ ((row & 7) << 4);
                    half8 a = as_h8(*(const short8*)(smw + (row << 10) + (byt >> 1)));
                    acc[rt] = __builtin_amdgcn_mfma_f32_16x16x32_f16(a, hb[j], acc[rt], 0, 0, 0);
                }
            }
            #pragma unroll
            for (int rt = 0; rt < 4; ++rt)
                #pragma unroll
                for (int r = 0; r < 4; ++r)
                    gl[wv][rt][rq + r][ml] = acc[rt][r];
            __syncthreads();   // B2
            // pointwise: thread (b, u) sums the 4 K-planes per gate
            float pre[4];
            #pragma unroll
            for (int q = 0; q < 4; ++q)
                pre[q] = gl[0][q][u][b] + gl[1][q][u][b] + gl[2][q][u][b] + gl[3][q][u][b]
                         + bs[q] + bf2f(emb[q]);
            float ii = sigm(pre[0]), ff = sigm(pre[1]);
            float gg = tanh_f(pre[2]), oo = sigm(pre[3]);
            float cc = ff * creg + ii * gg;
            creg = cc;
            ht[b][u] = f2h(oo * tanh_f(cc));
            __syncthreads();   // B3
            // WAVE 0 alone: coalesced publish -> per-wave vmcnt drain -> flag.
            // (vmcnt is per-wave and tid0 is in wave 0 => NO barrier needed;
            //  waves 1-3 fall through to the logit MFMAs during the drain.)
            if (tid < 32) {
                int b2 = tid >> 1, u8 = (tid & 1) << 3;
                unsigned long long lo = *(const unsigned long long*)&ht[b2][u8];
                unsigned long long hi;
                memcpy(&hi, &ht[b2][u8 + 4], 8);
                unsigned short* dst = hbase + (size_t)(p & (RING - 1)) * 16384
                                      + (iw << 8) + (b2 << 4) + u8;
                __hip_atomic_store((unsigned long long*)dst, lo, __ATOMIC_RELAXED, AGT);
                __hip_atomic_store((unsigned long long*)(dst + 4), hi, __ATOMIC_RELAXED, AGT);
                asm volatile("s_waitcnt vmcnt(0)" ::: "memory");  // wave-0 stores acked
                if (tid == 0)
                    __hip_atomic_store(gfl4 + iw, p, __ATOMIC_RELAXED, AGT);  // RELEASE
            }
        }

        // ---------------- logit phase for t = p-2 (uses hb = h_{p-1}) ----------------
        if (p >= 2) {
            f32x4 accl = {};
            #pragma unroll
            for (int j = 0; j < 8; ++j)
                accl = __builtin_amdgcn_mfma_f32_16x16x32_f16(la[j], hb[j], accl, 0, 0, 0);
            #pragma unroll
            for (int r = 0; r < 4; ++r)
                gl[wv][0][rq + r][ml] = accl[r];
            __syncthreads();   // B5
            // fused finalize + full-line stores on WAVE 1 (wave 0 stays store-free)
            if (tid >= 64 && tid < 128) {
                int vq = v0 + (sseg << 2);
                f32x4 val;
                #pragma unroll
                for (int r = 0; r < 4; ++r) {
                    int rowi = (sseg << 2) + r;
                    val[r] = gl[0][0][rowi][srow] + gl[1][0][rowi][srow]
                           + gl[2][0][rowi][srow] + gl[3][0][rowi][srow] + fbs[r];
                }
                float* po = out + ((size_t)(gB + srow) * TT + (p - 2)) * NV + vq;
                if (vq + 3 < NV) {
                    __builtin_nontemporal_store(val, (f32x4*)po);
                } else {
                    #pragma unroll
                    for (int r = 0; r < 4; ++r)
                        if (vq + r < NV) __builtin_nontemporal_store(val[r], po + r);
                }
            }
            // no trailing barrier: next iteration's B1 guards gl reuse
        }
    }
}

extern "C" void kernel_launch(void* const* d_in, const int* in_sizes, int n_in,
                              void* d_out, int out_size, void* d_ws, size_t ws_size,
                              hipStream_t stream) {
    const float* enc_h = (const float*)d_in[0];
    const float* enc_c = (const float*)d_in[1];
    const int* trg = (const int*)d_in[2];
    const float* Ww = (const float*)d_in[3];
    const float* Wb = (const float*)d_in[4];
    const float* fcw = (const float*)d_in[5];
    const float* fcb = (const float*)d_in[6];
    float* out = (float*)d_out;

    unsigned short* embT = (unsigned short*)d_ws;        // 1000 x 4096 bf16 (8 MB)
    unsigned short* hring = embT + (size_t)1000 * 4096;  // [4 grp][RING][16384] fp16

    const size_t embBytes = (size_t)1000 * 4096 * 2;
    const size_t slotBytes = (size_t)16384 * 2;
    const size_t need16 = embBytes + (size_t)NGRP * 16 * slotBytes + 8192;  // ~10.5 MB

    hipLaunchKernelGGL(embT_kernel, dim3(1024), dim3(256), 0, stream, Ww, embT);

    if (ws_size >= need16) {
        int* syn = (int*)(hring + (size_t)NGRP * 16 * 16384);
        hipMemsetAsync(syn, 0, 4096, stream);
        hipLaunchKernelGGL(h0_kernel, dim3(256), dim3(256), 0, stream, enc_h, hring, 16);
        lstm_kernel<16, 16><<<dim3(NGRP * GPW), dim3(256), 0, stream>>>(
            enc_c, trg, Ww, Wb, fcw, fcb, embT, hring, syn, out);
    } else {
        int* syn = (int*)(hring + (size_t)NGRP * 4 * 16384);
        hipMemsetAsync(syn, 0, 4096, stream);
        hipLaunchKernelGGL(h0_kernel, dim3(256), dim3(256), 0, stream, enc_h, hring, 4);
        lstm_kernel<4, 1><<<dim3(NGRP * GPW), dim3(256), 0, stream>>>(
            enc_c, trg, Ww, Wb, fcw, fcb, embT, hring, syn, out);
    }
}